// Round 3
// baseline (164.536 us; speedup 1.0000x reference)
//
#include <hip/hip_runtime.h>
#include <hip/hip_bf16.h>

// MyConvT: masked ConvTranspose2d, B=8, Cin=192, Cout=128, 64x64 -> 128x128,
// K=5, S=2, P=2, OP=1.  out = pooled_mask ? (convT(x,w) + bias) : 0
// Round 2: per-block output = 2 rows (oh=2oy, 2oy+1) x 128 ow x 128 co.
//   Weights A-frags: global->VGPR (L2-resident, 1.2MB). x B-frags: LDS,
//   3 input planes staged through a 2-slot pipeline (use order p2,p1,p0).
//   ci rows padded to 200 elems (400B) => conflict-free ds_read_b128, no swizzle.

#define NB   8
#define CIN  192
#define COUT 128
#define HH   64
#define WW   64
#define OHH  128
#define OWW  128
#define MH   132
#define MW   132

#define CIP     200                    // padded ci per x row (400 B)
#define XROWS   66                     // ixm = 0..65 (ix = -1..64, halo zeroed)
#define PLANE_B 26624                  // ceil(66*400/1024)*1024
#define PLANE_S (PLANE_B / 2)          // shorts
#define SLOT_B  PLANE_B
#define LDS_B   (2 * PLANE_B)          // 53,248 B; epilogue overlay 33,792 B

typedef short bf16x8 __attribute__((ext_vector_type(8)));
typedef float f32x4  __attribute__((ext_vector_type(4)));

static __device__ __forceinline__ unsigned short f2bf(float f) {
  union { float f; unsigned int u; } a; a.f = f;
  unsigned int u = a.u;
  return (unsigned short)((u + 0x7fffu + ((u >> 16) & 1u)) >> 16);   // RNE
}

#define GLOAD_LDS16(gp, lp) __builtin_amdgcn_global_load_lds(                      \
    (const __attribute__((address_space(1))) void*)(gp),                           \
    (__attribute__((address_space(3))) void*)(lp), 16, 0, 0)

// ---------------- mask 5x5 any-pool -> byte map [B][OH][OW] ----------------
__global__ __launch_bounds__(256) void pool_mask_k(const int* __restrict__ mask,
                                                   unsigned char* __restrict__ many) {
  int idx = blockIdx.x * 256 + threadIdx.x;
  if (idx >= NB * OHH * OWW) return;
  int ow = idx & (OWW - 1);
  int oh = (idx >> 7) & (OHH - 1);
  int b  = idx >> 14;
  const int* mp = mask + (b * MH + oh) * MW + ow;
  int any = 0;
  #pragma unroll
  for (int i = 0; i < 5; ++i)
    #pragma unroll
    for (int j = 0; j < 5; ++j)
      any |= mp[i * MW + j];
  many[idx] = (any != 0) ? 1 : 0;
}

// -- x transpose: [b][ci][iy][ix] f32 -> planes [b][iy][ixm 0..65][ci 200] bf16 --
__global__ __launch_bounds__(256) void xpose_k(const float* __restrict__ x,
                                               unsigned short* __restrict__ xt) {
  const int b = blockIdx.x >> 6, iy = blockIdx.x & 63;
  const int lane = threadIdx.x & 63, wv = threadIdx.x >> 6;
  unsigned short* pl = xt + (size_t)(b * HH + iy) * PLANE_S;

  // zero fills: 128 uint4 chunks (row0:25, row65:25, rows1..64 ci-pad:64, tail:14)
  const int t = threadIdx.x;
  if (t < 128) {
    int off16;                                     // 16B-chunk offset in plane
    if (t < 25)        off16 = t;                  // row 0
    else if (t < 50)   off16 = 65 * 25 + (t - 25); // row 65 (400B=25 chunks)
    else if (t < 114)  off16 = (1 + (t - 50)) * 25 + 24;  // ci 192..199 pad
    else               off16 = 66 * 25 + (t - 114);       // tail 26400..26623
    *(uint4*)((char*)pl + off16 * 16) = make_uint4(0, 0, 0, 0);
  }
  // data rows 1..64: lane -> ix; wave packs its 6 ci-chunks of 8
  #pragma unroll
  for (int k = 0; k < 6; ++k) {
    int ci0 = (wv * 6 + k) * 8;
    unsigned short p[8];
    #pragma unroll
    for (int e = 0; e < 8; ++e)
      p[e] = f2bf(x[(((size_t)b * CIN + ci0 + e) * HH + iy) * WW + lane]);
    uint4 v;
    v.x = (unsigned)p[0] | ((unsigned)p[1] << 16);
    v.y = (unsigned)p[2] | ((unsigned)p[3] << 16);
    v.z = (unsigned)p[4] | ((unsigned)p[5] << 16);
    v.w = (unsigned)p[6] | ((unsigned)p[7] << 16);
    *(uint4*)(pl + (size_t)(1 + lane) * CIP + ci0) = v;
  }
}

// ---- w repack: [ci][co][kh][kw] f32 -> [kh*5+kw][co][ci 192] bf16 ----
__global__ __launch_bounds__(256) void wpack_k(const float* __restrict__ w,
                                               unsigned short* __restrict__ wt) {
  int idx = blockIdx.x * 256 + threadIdx.x;     // 0..24575
  if (idx >= CIN * COUT) return;
  int ci = idx % CIN;
  int co = idx / CIN;
  const float* src = w + (size_t)(ci * COUT + co) * 25;
  #pragma unroll
  for (int t = 0; t < 25; ++t)
    wt[(size_t)t * (COUT * CIN) + co * CIN + ci] = f2bf(src[t]);
}

// ------------------------------ main kernel --------------------------------
// grid 512 = (oy 64) x (b 8), XCD-chunk swizzled. block 256 = 4 waves:
// wave = (coh = wv>>1: co half, pw = wv&1: ow parity). Each wave: 64 co x 64 owp.
__global__ __launch_bounds__(256, 2) void convt_mfma(
    const unsigned short* __restrict__ xt, const unsigned short* __restrict__ wt,
    const float* __restrict__ bias, const unsigned char* __restrict__ many,
    float* __restrict__ out) {
  __shared__ char xlds[LDS_B];

  const int tid = threadIdx.x, lane = tid & 63, wv = tid >> 6;
  // bijective XCD-chunk swizzle: consecutive oy on same XCD (512 = 8 XCD x 64)
  const int lid = (blockIdx.x & 7) * 64 + (blockIdx.x >> 3);
  const int b = lid & 7, oy = lid >> 3;
  const int pw = wv & 1, coh = wv >> 1;
  const int nkw = pw ? 2 : 3;
  const int l15 = lane & 15, kc = lane >> 4;

  // per-lane invariant part of the weight address (shorts)
  const size_t wlane = (size_t)(coh * 64 + l15) * CIN + kc * 8;

  f32x4 acc[2][4][4];
  #pragma unroll
  for (int p = 0; p < 2; ++p)
    #pragma unroll
    for (int i = 0; i < 4; ++i)
      #pragma unroll
      for (int j = 0; j < 4; ++j)
        acc[p][i][j] = (f32x4){0.f, 0.f, 0.f, 0.f};

  // ---- stage plane for step 0 (iy = oy+1) into slot 0 ----
  if (oy < 63) {
    const char* src = (const char*)(xt + (size_t)(b * HH + oy + 1) * PLANE_S);
    for (int i = wv; i < 26; i += 4)
      GLOAD_LDS16(src + i * 1024 + lane * 16, xlds + i * 1024);
  }
  __syncthreads();

  // ---- steps: step=kk uses plane iy=oy+1-step (slot step&1) ----
  #pragma unroll
  for (int step = 0; step < 3; ++step) {
    // issue next plane stage (after barrier => overlaps this step's compute)
    if (step < 2 && oy - step >= 0) {
      const char* src = (const char*)(xt + (size_t)(b * HH + oy - step) * PLANE_S);
      char* dst = xlds + ((step + 1) & 1) * SLOT_B;
      for (int i = wv; i < 26; i += 4)
        GLOAD_LDS16(src + i * 1024 + lane * 16, dst + i * 1024);
    }
    const int iy = oy + 1 - step;
    if (iy >= 0 && iy < HH) {                    // block-uniform validity
      const char* xs = xlds + (step & 1) * SLOT_B;
      const int nph = (step < 2) ? 2 : 1;        // step2: only ph=0 (kh=4)
      #pragma unroll
      for (int ph = 0; ph < 2; ++ph) {
        if (ph < nph) {
          const int kh = ph + 2 * step;
          for (int cic = 0; cic < 6; ++cic) {
            // A-fragments: global (L2) -> registers
            bf16x8 af[3][4];
            #pragma unroll
            for (int kj = 0; kj < 3; ++kj) {
              if (kj < nkw) {
                const int kw = pw + 2 * kj;
                const unsigned short* wp =
                    wt + wlane + (size_t)(kh * 5 + kw) * (COUT * CIN) + cic * 32;
                #pragma unroll
                for (int mi = 0; mi < 4; ++mi)
                  af[kj][mi] = *(const bf16x8*)(wp + mi * 16 * CIN);
              }
            }
            // B-fragments from LDS + MFMA
            #pragma unroll
            for (int kj = 0; kj < 3; ++kj) {
              if (kj < nkw) {
                #pragma unroll
                for (int ti = 0; ti < 4; ++ti) {
                  const int ixm = ti * 16 + l15 + 2 - kj;
                  bf16x8 bfr = *(const bf16x8*)(xs + ixm * 400 + cic * 64 + kc * 16);
                  #pragma unroll
                  for (int mi = 0; mi < 4; ++mi)
                    acc[ph][mi][ti] = __builtin_amdgcn_mfma_f32_16x16x32_bf16(
                        af[kj][mi], bfr, acc[ph][mi][ti], 0, 0, 0);
                }
              }
            }
          }
        }
      }
    }
    if (step < 2) __syncthreads();               // next stage done + slot free
  }

  // ---- epilogue: interleave parities via LDS, fuse bias+mask, coalesced store
  float* eps = (float*)xlds;                     // [64][132] f32 overlay
  #pragma unroll
  for (int ph = 0; ph < 2; ++ph) {
    const int oh = 2 * oy + ph;
    #pragma unroll
    for (int h = 0; h < 2; ++h) {
      __syncthreads();
      if (coh == h) {
        #pragma unroll
        for (int mi = 0; mi < 4; ++mi)
          #pragma unroll
          for (int ti = 0; ti < 4; ++ti)
            #pragma unroll
            for (int r = 0; r < 4; ++r) {
              int row = mi * 16 + kc * 4 + r;
              int ow  = ((ti * 16 + l15) << 1) | pw;
              eps[row * 132 + ow] = acc[ph][mi][ti][r];
            }
      }
      __syncthreads();
      {
        int r = tid >> 2, q = tid & 3;
        int co = h * 64 + r;
        float bv = bias[co];
        const unsigned char* mrow = many + ((size_t)b * OHH + oh) * OWW + q * 32;
        float* orow = out + (((size_t)(b * COUT + co)) * OHH + oh) * OWW + q * 32;
        #pragma unroll
        for (int j = 0; j < 8; ++j) {
          f32x4 v = *(const f32x4*)(eps + r * 132 + q * 32 + j * 4);
          unsigned int m4 = *(const unsigned int*)(mrow + j * 4);
          f32x4 o;
          o.x = (m4 & 0x000000FFu) ? v.x + bv : 0.f;
          o.y = (m4 & 0x0000FF00u) ? v.y + bv : 0.f;
          o.z = (m4 & 0x00FF0000u) ? v.z + bv : 0.f;
          o.w = (m4 & 0xFF000000u) ? v.w + bv : 0.f;
          *(f32x4*)(orow + j * 4) = o;
        }
      }
    }
  }
}

extern "C" void kernel_launch(void* const* d_in, const int* in_sizes, int n_in,
                              void* d_out, int out_size, void* d_ws, size_t ws_size,
                              hipStream_t stream) {
  const float* x    = (const float*)d_in[0];
  const int*   mask = (const int*)d_in[1];
  const float* w    = (const float*)d_in[2];
  const float* bias = (const float*)d_in[3];
  float* out = (float*)d_out;

  // ws: many 128KB | xt planes 13.63MB | wt 1.23MB  (~15MB)
  unsigned char*  many = (unsigned char*)d_ws;
  unsigned short* xt   = (unsigned short*)((char*)d_ws + 131072);
  unsigned short* wt   = (unsigned short*)((char*)d_ws + 131072 +
                                           (size_t)NB * HH * PLANE_B);

  pool_mask_k<<<(NB * OHH * OWW + 255) / 256, 256, 0, stream>>>(mask, many);
  xpose_k<<<NB * HH, 256, 0, stream>>>(x, xt);
  wpack_k<<<(CIN * COUT + 255) / 256, 256, 0, stream>>>(w, wt);
  convt_mfma<<<NB * HH, 256, 0, stream>>>(xt, wt, bias, many, out);
}

// Round 4
// 102.641 us; speedup vs baseline: 1.6030x; 1.6030x over previous
//
#include <hip/hip_runtime.h>
#include <hip/hip_bf16.h>

// MyConvT: masked ConvTranspose2d, B=8, Cin=192, Cout=128, 64x64 -> 128x128,
// K=5, S=2, P=2, OP=1.  out = pooled_mask ? (convT(x,w) + bias) : 0
// Round 3: block = (b, oy-pair): M=128co x N=512 (2oy x 2ph x 128ow).
//   grid 256 = 1 block/CU, 16 waves. x: 4 planes resident in LDS (106KB).
//   Weights: 75-step K-loop (3 ci64 x 25 taps), 16KB tile/step, 3-slot ring,
//   global_load_lds 2 steps ahead, counted vmcnt(1) + raw s_barrier (T3/T4).
//   A-tile XOR-swizzled (T2) via inverse-permuted global source (rule 21).

#define NB   8
#define CIN  192
#define COUT 128
#define HH   64
#define WW   64
#define OHH  128
#define OWW  128
#define MH   132
#define MW   132

#define CIP     200                    // padded ci per x row (400 B)
#define PLANE_B 26624                  // ceil(66*400/1024)*1024
#define PLANE_S (PLANE_B / 2)
#define WT_TAP  (COUT * CIN)           // 24576 shorts per tap

#define PLN_OFF  0
#define WBUF_OFF (4 * PLANE_B)         // 106,496
#define WSLOT_B  16384
#define LDS_B    (WBUF_OFF + 3 * WSLOT_B)   // 155,648 <= 160K

typedef short bf16x8 __attribute__((ext_vector_type(8)));
typedef float f32x4  __attribute__((ext_vector_type(4)));
typedef float f32x2  __attribute__((ext_vector_type(2)));

static __device__ __forceinline__ unsigned short f2bf(float f) {
  union { float f; unsigned int u; } a; a.f = f;
  unsigned int u = a.u;
  return (unsigned short)((u + 0x7fffu + ((u >> 16) & 1u)) >> 16);   // RNE
}

#define GLOAD_LDS16(gp, lp) __builtin_amdgcn_global_load_lds(                      \
    (const __attribute__((address_space(1))) void*)(gp),                           \
    (__attribute__((address_space(3))) void*)(lp), 16, 0, 0)

// ---------------- mask 5x5 any-pool -> byte map [B][OH][OW] ----------------
__global__ __launch_bounds__(256) void pool_mask_k(const int* __restrict__ mask,
                                                   unsigned char* __restrict__ many) {
  int idx = blockIdx.x * 256 + threadIdx.x;
  if (idx >= NB * OHH * OWW) return;
  int ow = idx & (OWW - 1);
  int oh = (idx >> 7) & (OHH - 1);
  int b  = idx >> 14;
  const int* mp = mask + (b * MH + oh) * MW + ow;
  int any = 0;
  #pragma unroll
  for (int i = 0; i < 5; ++i)
    #pragma unroll
    for (int j = 0; j < 5; ++j)
      any |= mp[i * MW + j];
  many[idx] = (any != 0) ? 1 : 0;
}

// -- x transpose: [b][ci][iy][ix] f32 -> planes [b][iy][ixm 0..65][ci 200] bf16 --
__global__ __launch_bounds__(256) void xpose_k(const float* __restrict__ x,
                                               unsigned short* __restrict__ xt) {
  const int b = blockIdx.x >> 6, iy = blockIdx.x & 63;
  const int lane = threadIdx.x & 63, wv = threadIdx.x >> 6;
  unsigned short* pl = xt + (size_t)(b * HH + iy) * PLANE_S;

  const int t = threadIdx.x;
  if (t < 128) {
    int off16;                                     // 16B-chunk offset in plane
    if (t < 25)        off16 = t;                  // row 0 (ix = -1)
    else if (t < 50)   off16 = 65 * 25 + (t - 25); // row 65 (ix = 64)
    else if (t < 114)  off16 = (1 + (t - 50)) * 25 + 24;  // ci 192..199 pad
    else               off16 = 66 * 25 + (t - 114);       // tail to 26624
    *(uint4*)((char*)pl + off16 * 16) = make_uint4(0, 0, 0, 0);
  }
  #pragma unroll
  for (int k = 0; k < 6; ++k) {
    int ci0 = (wv * 6 + k) * 8;
    unsigned short p[8];
    #pragma unroll
    for (int e = 0; e < 8; ++e)
      p[e] = f2bf(x[(((size_t)b * CIN + ci0 + e) * HH + iy) * WW + lane]);
    uint4 v;
    v.x = (unsigned)p[0] | ((unsigned)p[1] << 16);
    v.y = (unsigned)p[2] | ((unsigned)p[3] << 16);
    v.z = (unsigned)p[4] | ((unsigned)p[5] << 16);
    v.w = (unsigned)p[6] | ((unsigned)p[7] << 16);
    *(uint4*)(pl + (size_t)(1 + lane) * CIP + ci0) = v;
  }
}

// ---- w repack: [ci][co][kh][kw] f32 -> [kh*5+kw][co][ci 192] bf16 ----
__global__ __launch_bounds__(256) void wpack_k(const float* __restrict__ w,
                                               unsigned short* __restrict__ wt) {
  int idx = blockIdx.x * 256 + threadIdx.x;
  if (idx >= CIN * COUT) return;
  int ci = idx % CIN;
  int co = idx / CIN;
  const float* src = w + (size_t)(ci * COUT + co) * 25;
  #pragma unroll
  for (int t = 0; t < 25; ++t)
    wt[(size_t)t * WT_TAP + co * CIN + ci] = f2bf(src[t]);
}

// ------------------------------ main kernel --------------------------------
// grid 256 = (b 8) x (oyq 32); 1024 thr = 16 waves.
// wave fields: coh=wv&1, oys=(wv>>1)&1, pw=(wv>>2)&1, ph=wv>>3
//   -> per step the 4 active waves (fixed ph,pw) sit on 4 different SIMDs.
__global__ __launch_bounds__(1024, 4) void convt_mfma(
    const unsigned short* __restrict__ xt, const unsigned short* __restrict__ wt,
    const float* __restrict__ bias, const unsigned char* __restrict__ many,
    float* __restrict__ out) {
  __shared__ char lds[LDS_B];

  const int tid = threadIdx.x, lane = tid & 63, wv = tid >> 6;
  const int l15 = lane & 15, kc = lane >> 4;
  const int coh = wv & 1, oys = (wv >> 1) & 1, pw = (wv >> 2) & 1, ph = wv >> 3;

  // XCD-chunk swizzle: 256 = 8 XCD x 32; same-b blocks share an XCD's L2.
  const int sw  = (blockIdx.x & 7) * 32 + (blockIdx.x >> 3);
  const int b   = sw >> 5, oyq = sw & 31, oy0 = oyq * 2;

  // ---------------- prologue: stage 4 planes + wbuf steps 0,1 ----------------
  for (int c = wv; c < 104; c += 16) {              // 104 x 1KB plane chunks
    int slot = c / 26, off = c % 26;
    int iy = oy0 - 1 + slot;
    char* dst = lds + PLN_OFF + slot * PLANE_B + off * 1024;
    if (iy >= 0 && iy < HH) {
      const char* src = (const char*)(xt + (size_t)(b * HH + iy) * PLANE_S) + off * 1024;
      GLOAD_LDS16(src + lane * 16, dst);
    } else {
      *(f32x4*)(dst + lane * 16) = (f32x4){0.f, 0.f, 0.f, 0.f};  // zero halo plane
    }
  }
  // weight stage source: wave wv stages chunk wv (1KB) of each 16KB tile.
  // LDS element (co,ci64): byte L = co*128 + ((ci*2) ^ ((co&7)<<4))  [T2 swizzle]
  // linear chunk write => inverse-permuted global source (rule 21):
  const int s_co = wv * 8 + (lane >> 3);
  const int s_ci = ((lane & 7) ^ (lane >> 3)) * 8;  // (co&7) == lane>>3 here
  const unsigned short* wsrc0 = wt + s_co * CIN + s_ci;

  {  // stage steps 0 and 1: (tap=0,c2=0), (tap=1,c2=0)
    GLOAD_LDS16(wsrc0 + 0 * WT_TAP, lds + WBUF_OFF + 0 * WSLOT_B + wv * 1024);
    GLOAD_LDS16(wsrc0 + 1 * WT_TAP, lds + WBUF_OFF + 1 * WSLOT_B + wv * 1024);
  }
  asm volatile("s_waitcnt lgkmcnt(0)" ::: "memory");  // zero-plane ds_writes drained
  asm volatile("s_waitcnt vmcnt(1)" ::: "memory");    // planes + w0 done (w1 in flight)
  __builtin_amdgcn_s_barrier();

  // per-lane read offsets
  const int afo0 = coh * 8192 + l15 * 128 + (((0 * 4 + kc) ^ (l15 & 7)) << 4);
  const int afo1 = coh * 8192 + l15 * 128 + (((1 * 4 + kc) ^ (l15 & 7)) << 4);
  const int bfo  = l15 * 400 + kc * 16;

  f32x4 acc[4][4];
  #pragma unroll
  for (int i = 0; i < 4; ++i)
    #pragma unroll
    for (int j = 0; j < 4; ++j)
      acc[i][j] = (f32x4){0.f, 0.f, 0.f, 0.f};

  // ---------------- K-loop: 75 steps = 3 ci64 x 25 taps ----------------
  int kh = 0, kw = 0, c2 = 0;          // current step indices
  int t2 = 2, cc2 = 0;                 // stage-ahead (s+2) tap / ci64
  int ws3 = 0;                         // s % 3
  #pragma unroll 1
  for (int s = 0; s < 75; ++s) {
    const bool do_stage = (s + 2 < 75);
    if (do_stage) {
      GLOAD_LDS16(wsrc0 + (size_t)t2 * WT_TAP + cc2 * 64,
                  lds + WBUF_OFF + ((ws3 + 2) % 3) * WSLOT_B + wv * 1024);
    }
    if ((kh & 1) == ph && (kw & 1) == pw) {          // wave-uniform
      const int kk = kh >> 1, kj = kw >> 1;
      const int slot = oys + 2 - kk;
      const char* ws = lds + WBUF_OFF + ws3 * WSLOT_B;
      const char* ps = lds + PLN_OFF + slot * PLANE_B + (2 - kj) * 400 + c2 * 128 + bfo;
      __builtin_amdgcn_s_setprio(1);
      #pragma unroll
      for (int k2 = 0; k2 < 2; ++k2) {
        const char* wsk = ws + (k2 ? afo1 : afo0);
        bf16x8 af[4], bf[4];
        #pragma unroll
        for (int mi = 0; mi < 4; ++mi) af[mi] = *(const bf16x8*)(wsk + mi * 2048);
        #pragma unroll
        for (int ti = 0; ti < 4; ++ti) bf[ti] = *(const bf16x8*)(ps + ti * 6400 + k2 * 64);
        #pragma unroll
        for (int mi = 0; mi < 4; ++mi)
          #pragma unroll
          for (int ti = 0; ti < 4; ++ti)
            acc[mi][ti] = __builtin_amdgcn_mfma_f32_16x16x32_bf16(
                af[mi], bf[ti], acc[mi][ti], 0, 0, 0);
      }
      __builtin_amdgcn_s_setprio(0);
    }
    if (do_stage) asm volatile("s_waitcnt vmcnt(1)" ::: "memory");  // s+1 tile ready
    else          asm volatile("s_waitcnt vmcnt(0)" ::: "memory");  // tail drain
    __builtin_amdgcn_s_barrier();
    // advance counters
    if (++kw == 5) { kw = 0; if (++kh == 5) { kh = 0; ++c2; } }
    if (++t2 == 25) { t2 = 0; ++cc2; }
    if (++ws3 == 3) ws3 = 0;
  }

  // ---------------- epilogue: 4 passes (oys_p, ph_p) ----------------
  // eps layout: [co 128][pw 2][owp 64 + 2 pad] f32  (67,584 B overlay on planes)
  float* eps = (float*)(lds + PLN_OFF);
  const int tco = tid >> 3, q = tid & 7;
  const float bv = bias[tco];
  #pragma unroll 1
  for (int p = 0; p < 4; ++p) {
    const int ph_p = p & 1, oys_p = p >> 1;
    __syncthreads();
    if (oys == oys_p && ph == ph_p) {
      #pragma unroll
      for (int mi = 0; mi < 4; ++mi)
        #pragma unroll
        for (int ti = 0; ti < 4; ++ti)
          #pragma unroll
          for (int r = 0; r < 4; ++r)
            eps[(coh * 64 + mi * 16 + kc * 4 + r) * 132 + pw * 66 + ti * 16 + l15] =
                acc[mi][ti][r];
    }
    __syncthreads();
    const int oh = (oy0 + oys_p) * 2 + ph_p;
    const unsigned char* mrow = many + ((size_t)b * OHH + oh) * OWW + q * 16;
    float* orow = out + (((size_t)(b * COUT + tco)) * OHH + oh) * OWW + q * 16;
    const float* e0 = eps + tco * 132 + q * 8;
    #pragma unroll
    for (int j = 0; j < 4; ++j) {
      f32x2 A = *(const f32x2*)(e0 + 2 * j);            // pw=0 pair
      f32x2 B = *(const f32x2*)(e0 + 66 + 2 * j);       // pw=1 pair
      unsigned int m4 = *(const unsigned int*)(mrow + 4 * j);
      f32x4 o;
      o.x = (m4 & 0x000000FFu) ? A.x + bv : 0.f;
      o.y = (m4 & 0x0000FF00u) ? B.x + bv : 0.f;
      o.z = (m4 & 0x00FF0000u) ? A.y + bv : 0.f;
      o.w = (m4 & 0xFF000000u) ? B.y + bv : 0.f;
      *(f32x4*)(orow + 4 * j) = o;
    }
  }
}

extern "C" void kernel_launch(void* const* d_in, const int* in_sizes, int n_in,
                              void* d_out, int out_size, void* d_ws, size_t ws_size,
                              hipStream_t stream) {
  const float* x    = (const float*)d_in[0];
  const int*   mask = (const int*)d_in[1];
  const float* w    = (const float*)d_in[2];
  const float* bias = (const float*)d_in[3];
  float* out = (float*)d_out;

  // ws: many 128KB | xt planes 13.63MB | wt 1.23MB  (~15MB)
  unsigned char*  many = (unsigned char*)d_ws;
  unsigned short* xt   = (unsigned short*)((char*)d_ws + 131072);
  unsigned short* wt   = (unsigned short*)((char*)d_ws + 131072 +
                                           (size_t)NB * HH * PLANE_B);

  pool_mask_k<<<(NB * OHH * OWW + 255) / 256, 256, 0, stream>>>(mask, many);
  xpose_k<<<NB * HH, 256, 0, stream>>>(x, xt);
  wpack_k<<<(CIN * COUT + 255) / 256, 256, 0, stream>>>(w, wt);
  convt_mfma<<<NB * HH / 2, 1024, 0, stream>>>(xt, wt, bias, many, out);
}

// Round 5
// 75.230 us; speedup vs baseline: 2.1871x; 1.3644x over previous
//
#include <hip/hip_runtime.h>

// MyConvT: masked ConvTranspose2d, B=8, Cin=192, Cout=128, 64x64 -> 128x128,
// K=5, S=2, P=2, OP=1.  out = pooled_mask ? (convT(x,w) + bias) : 0
// Round 4: per-parity-class blocks. Class (ph,pw) = GEMM M=128co x N=32768 x
// K=192*taps. 512 blocks = 128/class (dispatch-ordered for CU balance).
// Block: 128co x 4 rows x 64 cols; 8 waves; wave = 64co x 64out (mi4 x nt4).
// Every wave: 32 MFMA + 16 ds_read_b128 per K-step. x: 6-plane 55KB LDS
// double-buffer per ci64 round; w: 16KB tiles, 3-slot ring, staged 2 ahead,
// counted vmcnt (T3/T4). XOR-swizzled LDS via inverse-permuted global src.

#define NB   8
#define CIN  192
#define COUT 128
#define HH   64
#define WW   64
#define OHH  128
#define OWW  128
#define MH   132
#define MW   132

#define XPLN_G   (66 * CIN)              // shorts per global x plane (12672)
#define WT_TAP   (COUT * CIN)            // 24576 shorts per tap

#define XPLANE_LB 9216                   // LDS bytes per plane (72 rows x 128B)
#define XBUF_B    (6 * XPLANE_LB)        // 55296
#define WR_OFF    (2 * XBUF_B)           // 110592
#define WSLOT_B   16384
#define LDS_B     (WR_OFF + 3 * WSLOT_B) // 159744 <= 160K

typedef short bf16x8 __attribute__((ext_vector_type(8)));
typedef float f32x4  __attribute__((ext_vector_type(4)));

static __device__ __forceinline__ unsigned short f2bf(float f) {
  union { float f; unsigned int u; } a; a.f = f;
  return (unsigned short)((a.u + 0x7fffu + ((a.u >> 16) & 1u)) >> 16);   // RNE
}

#define GLOAD_LDS16(gp, lp) __builtin_amdgcn_global_load_lds(                      \
    (const __attribute__((address_space(1))) void*)(gp),                           \
    (__attribute__((address_space(3))) void*)(lp), 16, 0, 0)

// ---------------- mask 5x5 any-pool -> byte map [B][OH][OW] ----------------
__global__ __launch_bounds__(256) void pool_mask_k(const int* __restrict__ mask,
                                                   unsigned char* __restrict__ many) {
  int idx = blockIdx.x * 256 + threadIdx.x;
  if (idx >= NB * OHH * OWW) return;
  int ow = idx & (OWW - 1);
  int oh = (idx >> 7) & (OHH - 1);
  int b  = idx >> 14;
  const int* mp = mask + (b * MH + oh) * MW + ow;
  int any = 0;
  #pragma unroll
  for (int i = 0; i < 5; ++i)
    #pragma unroll
    for (int j = 0; j < 5; ++j)
      any |= mp[i * MW + j];
  many[idx] = (any != 0) ? 1 : 0;
}

// x transpose: [b][ci][iy][ix] f32 -> [b][iyH 0..65][ixm 0..65][ci 192] bf16
// iyH = iy+1 (planes 0,65 = zero halo); ixm = ix+1 (cols 0,65 = zero halo).
__global__ __launch_bounds__(256) void xpose_k(const float* __restrict__ x,
                                               unsigned short* __restrict__ xt) {
  const int b = blockIdx.x / 66, iyH = blockIdx.x % 66;
  const int lane = threadIdx.x & 63, wv = threadIdx.x >> 6;
  unsigned short* pl = xt + (size_t)(b * 66 + iyH) * XPLN_G;

  if (iyH == 0 || iyH == 65) {                       // zero halo plane
    for (int i = threadIdx.x; i < XPLN_G / 8; i += 256)
      *(uint4*)(pl + i * 8) = make_uint4(0, 0, 0, 0);
    return;
  }
  const int iy = iyH - 1;
  if (threadIdx.x < 48) {                            // zero halo cols (rows 0,65)
    int row = threadIdx.x < 24 ? 0 : 65, ch = threadIdx.x % 24;
    *(uint4*)(pl + row * CIN + ch * 8) = make_uint4(0, 0, 0, 0);
  }
  #pragma unroll
  for (int k = 0; k < 6; ++k) {
    int ci0 = wv * 48 + k * 8;
    unsigned short p[8];
    #pragma unroll
    for (int e = 0; e < 8; ++e)
      p[e] = f2bf(x[(((size_t)b * CIN + ci0 + e) * HH + iy) * WW + lane]);
    uint4 v;
    v.x = (unsigned)p[0] | ((unsigned)p[1] << 16);
    v.y = (unsigned)p[2] | ((unsigned)p[3] << 16);
    v.z = (unsigned)p[4] | ((unsigned)p[5] << 16);
    v.w = (unsigned)p[6] | ((unsigned)p[7] << 16);
    *(uint4*)(pl + (size_t)(1 + lane) * CIN + ci0) = v;
  }
}

// ---- w repack: [ci][co][kh][kw] f32 -> [kh*5+kw][co][ci 192] bf16 ----
__global__ __launch_bounds__(256) void wpack_k(const float* __restrict__ w,
                                               unsigned short* __restrict__ wt) {
  int idx = blockIdx.x * 256 + threadIdx.x;
  if (idx >= CIN * COUT) return;
  int ci = idx % CIN;
  int co = idx / CIN;
  const float* src = w + (size_t)(ci * COUT + co) * 25;
  #pragma unroll
  for (int t = 0; t < 25; ++t)
    wt[(size_t)t * WT_TAP + co * CIN + ci] = f2bf(src[t]);
}

// ------------------------------ main kernel --------------------------------
template<int PH, int PW>
__device__ __forceinline__ void conv_class(
    const unsigned short* __restrict__ xt, const unsigned short* __restrict__ wt,
    const float* __restrict__ bias, const unsigned char* __restrict__ many,
    float* __restrict__ out, char* lds, int idx) {
  constexpr int NKW = PW ? 2 : 3;
  constexpr int NKK = PH ? 2 : 3;
  constexpr int T = NKK * NKW;                 // taps in this class
  constexpr int S = 3 * T;                     // flat K-steps

  const int tid = threadIdx.x, lane = tid & 63, wv = tid >> 6;
  const int l15 = lane & 15, kc = lane >> 4;
  const int lo8 = lane >> 3, l7 = lane & 7;
  const int coh = wv & 1, rowq = wv >> 1;      // wave: co half, row in group
  const int b = idx & 7, g4 = (idx >> 3) * 4;  // batch, row-group base (oy)
  const int oy = g4 + rowq;

  // lane-const LDS read offsets (XOR bank swizzle baked in)
  int A0[2], B0[3][2];
  #pragma unroll
  for (int k2 = 0; k2 < 2; ++k2) {
    A0[k2] = (coh * 64 + l15) * 128 + (((kc + 4 * k2) ^ (l15 & 7)) << 4);
    #pragma unroll
    for (int kj = 0; kj < 3; ++kj) {
      int im = l15 + 2 - kj;
      B0[kj][k2] = im * 128 + (((kc + 4 * k2) ^ (im & 7)) << 4);
    }
  }
  // stage-source lane permutation (inverse of the read-side XOR swizzle)
  const int wlaneo = lo8 * CIN + ((l7 ^ lo8) << 3);
  const unsigned short* xgb = xt + (size_t)(b * 66 + g4) * XPLN_G;  // plane iyH=g4+p

  auto stage_x = [&](int c2x) {
    char* xdst = lds + (c2x & 1) * XBUF_B;
    #pragma unroll
    for (int j = 0; j < 7; ++j) {
      int cid = wv + 8 * j;
      if (cid >= 54) cid -= 54;                // waves 6,7: dup chunks 0,1 (benign)
      const int p = cid / 9, jj = cid % 9;
      const unsigned short* s = xgb + (size_t)p * XPLN_G + (jj * 8 + lo8) * CIN
                                + c2x * 64 + ((l7 ^ lo8) << 3);
      GLOAD_LDS16(s, xdst + cid * 1024);
    }
  };
  auto stage_w = [&](int tapid, int c2p, int ring2) {
    const unsigned short* s = wt + (size_t)tapid * WT_TAP + (wv * 16) * CIN
                              + c2p * 64 + wlaneo;
    char* d = lds + WR_OFF + ring2 * WSLOT_B + wv * 2048;
    GLOAD_LDS16(s, d);
    GLOAD_LDS16(s + 8 * CIN, d + 1024);
  };
  auto tapid_of = [](int t) {
    return (PH + 2 * (t / NKW)) * 5 + PW + 2 * (t % NKW);
  };

  f32x4 acc[4][4];
  #pragma unroll
  for (int i = 0; i < 4; ++i)
    #pragma unroll
    for (int j = 0; j < 4; ++j)
      acc[i][j] = (f32x4){0.f, 0.f, 0.f, 0.f};

  // ---- prologue: x round 0 + w steps 0,1 ----
  stage_x(0);
  stage_w(tapid_of(0), 0, 0);
  stage_w(tapid_of(1), 0, 1);
  asm volatile("s_waitcnt vmcnt(2)" ::: "memory");   // x0 + w0 done; w1 in flight
  __builtin_amdgcn_s_barrier();

  // ---- flat K-loop: s = c2*T + t ----
  #pragma unroll 1
  for (int c2 = 0; c2 < 3; ++c2) {
    const char* xb = lds + (c2 & 1) * XBUF_B;
    #pragma unroll
    for (int t = 0; t < T; ++t) {
      const bool hook  = (t == 0) && (c2 < 2);
      const bool last2 = (c2 == 2) && (t >= T - 2);
      if (hook) stage_x(c2 + 1);
      if (!last2) {
        int t2 = t + 2, c2p = c2;
        if (t2 >= T) { t2 -= T; c2p += 1; }
        const int ring2 = (T % 3 == 0) ? (t2 % 3) : ((c2p * T + t2) % 3);
        stage_w(tapid_of(t2), c2p, ring2);
      }
      // ---- compute tap t of round c2 ----
      {
        const int kk = t / NKW, kj = t % NKW;
        const int ring = (T % 3 == 0) ? (t % 3) : ((c2 * T + t) % 3);
        const char* wsl = lds + WR_OFF + ring * WSLOT_B;
        const char* xp  = xb + (rowq + 2 - kk) * XPLANE_LB;
        bf16x8 af[4], bf[4];
        #pragma unroll
        for (int k2 = 0; k2 < 2; ++k2) {
          #pragma unroll
          for (int mi = 0; mi < 4; ++mi) af[mi] = *(const bf16x8*)(wsl + mi * 2048 + A0[k2]);
          #pragma unroll
          for (int ti = 0; ti < 4; ++ti) bf[ti] = *(const bf16x8*)(xp + ti * 2048 + B0[kj][k2]);
          __builtin_amdgcn_s_setprio(1);
          #pragma unroll
          for (int mi = 0; mi < 4; ++mi)
            #pragma unroll
            for (int ti = 0; ti < 4; ++ti)
              acc[mi][ti] = __builtin_amdgcn_mfma_f32_16x16x32_bf16(
                  af[mi], bf[ti], acc[mi][ti], 0, 0, 0);
          __builtin_amdgcn_s_setprio(0);
        }
      }
      // ---- end-of-step wait (counted; never 0 mid-loop) + barrier ----
      if (hook)                asm volatile("s_waitcnt vmcnt(9)" ::: "memory");
      else if (!last2)         asm volatile("s_waitcnt vmcnt(2)" ::: "memory");
      else if (t == T - 2)     asm volatile("s_waitcnt vmcnt(0)" ::: "memory");
      if (!(c2 == 2 && t == T - 1)) __builtin_amdgcn_s_barrier();
    }
  }

  // ---- epilogue: direct register stores, bias+mask fused ----
  const int oh = 2 * oy + PH;
  unsigned char mb[4];
  const unsigned char* mrow = many + ((size_t)b * OHH + oh) * OWW + PW;
  #pragma unroll
  for (int ti = 0; ti < 4; ++ti) mb[ti] = mrow[2 * (ti * 16 + l15)];
  float* ob = out + (((size_t)(b * COUT + coh * 64)) * OHH + oh) * OWW + PW;
  #pragma unroll
  for (int mi = 0; mi < 4; ++mi) {
    #pragma unroll
    for (int r = 0; r < 4; ++r) {
      const int co_off = mi * 16 + kc * 4 + r;
      const float bvv = bias[coh * 64 + co_off];
      float* orow = ob + (size_t)co_off * (OHH * OWW);
      #pragma unroll
      for (int ti = 0; ti < 4; ++ti)
        orow[2 * (ti * 16 + l15)] = mb[ti] ? acc[mi][ti][r] + bvv : 0.f;
    }
  }
}

// grid 512: blocks [0,128)=class(0,0), [128,256)=(0,1), [256,384)=(1,0),
// [384,512)=(1,1) — dispatch order pairs heavy+light per CU.
// within class: idx = b + 8*g  (consecutive dispatch cycles b => XCD ~ batch).
__global__ __launch_bounds__(512, 2) void convt_mfma(
    const unsigned short* __restrict__ xt, const unsigned short* __restrict__ wt,
    const float* __restrict__ bias, const unsigned char* __restrict__ many,
    float* __restrict__ out) {
  __shared__ char lds[LDS_B];
  const int ord = blockIdx.x >> 7, idx = blockIdx.x & 127;
  if      (ord == 0) conv_class<0, 0>(xt, wt, bias, many, out, lds, idx);
  else if (ord == 1) conv_class<0, 1>(xt, wt, bias, many, out, lds, idx);
  else if (ord == 2) conv_class<1, 0>(xt, wt, bias, many, out, lds, idx);
  else               conv_class<1, 1>(xt, wt, bias, many, out, lds, idx);
}

extern "C" void kernel_launch(void* const* d_in, const int* in_sizes, int n_in,
                              void* d_out, int out_size, void* d_ws, size_t ws_size,
                              hipStream_t stream) {
  const float* x    = (const float*)d_in[0];
  const int*   mask = (const int*)d_in[1];
  const float* w    = (const float*)d_in[2];
  const float* bias = (const float*)d_in[3];
  float* out = (float*)d_out;

  // ws: many 128KB | xt 8*66 planes bf16 (12.77MB + 4KB slack) | wt 1.23MB
  unsigned char*  many = (unsigned char*)d_ws;
  unsigned short* xt   = (unsigned short*)((char*)d_ws + 131072);
  unsigned short* wt   = (unsigned short*)((char*)d_ws + 131072 +
                                           (size_t)NB * 66 * XPLN_G * 2 + 4096);

  pool_mask_k<<<(NB * OHH * OWW + 255) / 256, 256, 0, stream>>>(mask, many);
  xpose_k<<<NB * 66, 256, 0, stream>>>(x, xt);
  wpack_k<<<(CIN * COUT + 255) / 256, 256, 0, stream>>>(w, wt);
  convt_mfma<<<512, 512, 0, stream>>>(xt, wt, bias, many, out);
}